// Round 11
// baseline (865.765 us; speedup 1.0000x reference)
//
#include <hip/hip_runtime.h>

#define BATCH 2
#define NH    16
#define SEQ   2048
#define DH    64
#define KT    32
#define NKT   (SEQ / KT)    // 64 k-tiles

typedef __attribute__((ext_vector_type(8))) short          bf16x8;
typedef __attribute__((ext_vector_type(4))) float          f32x4;
typedef __attribute__((ext_vector_type(4))) unsigned int   u32x4;
typedef __attribute__((ext_vector_type(4))) int            i32x4;

__device__ __forceinline__ unsigned short f2bf(float f) {   // RNE
    union { float f; unsigned int i; } c;
    c.f = f;
    unsigned int x = c.i;
    x += 0x7fffu + ((x >> 16) & 1u);
    return (unsigned short)(x >> 16);
}
// truncation pack: two f32 -> one u32 of 2 bf16 (round-toward-zero; cheap)
__device__ __forceinline__ unsigned int pkt(float lo, float hi) {
    union { float f; unsigned int u; } a, b;
    a.f = lo; b.f = hi;
    return (b.u & 0xFFFF0000u) | (a.u >> 16);
}

template<bool ISBYTE> struct RawT {
    f32x4 k[2][4];          // [mb][a0lo,a0hi,a1lo,a1hi]
    f32x4 bias[2];
    unsigned int m8[2];     // ISBYTE
    i32x4 mi[2];            // !ISBYTE
};

// ================= kernel 1: scores. attn <- UNNORMALIZED exp(s); rinv -> ws ==========
// 2 independent waves/block, each owns 16 q-rows x full k. No LDS, no V, short chain.
template<bool ISBYTE>
__global__ __launch_bounds__(128)
void sdpa_score(const float* __restrict__ qp,
                const float* __restrict__ kp,
                const void*  __restrict__ mp,
                const float* __restrict__ bp,
                float* __restrict__ attnp,
                float* __restrict__ rinvp)
{
    const int tid  = threadIdx.x;
    const int wid  = tid >> 6;
    const int lane = tid & 63;
    const int l15  = lane & 15;         // q-column (S^T layout of QK^T)
    const int g    = lane >> 4;

    const unsigned int* mw = (const unsigned int*)mp;
    if ((__any((int)(mw[lane & 31] > 1u)) != 0) != ISBYTE) return;

    // XCD swizzle (2 heads/XCD) + b interleaved so bias rows pair-share in L2
    const int bid  = blockIdx.x;
    const int orig = (bid & 7) * 256 + (bid >> 3);   // bijective, 2048 blocks
    const int h    = orig >> 7;
    const int w_   = orig & 127;
    const int qtg  = w_ >> 1;
    const int b    = w_ & 1;
    const int qt   = qtg * 2 + wid;
    const int bh   = b * NH + h;
    const int qrow = qt * 16 + l15;

    const float* kbh = kp + (size_t)bh * SEQ * DH;
    const float* biasRow = bp + ((size_t)h * SEQ + qrow) * SEQ;                  // [1,H,S,S]
    const unsigned char* maskRowB = (const unsigned char*)mp + ((size_t)b * SEQ + qrow) * SEQ;
    const int*           maskRowI = (const int*)mp + ((size_t)b * SEQ + qrow) * SEQ;
    float* attnRow = attnp + ((size_t)bh * SEQ + qrow) * SEQ;

    // Q fragments (B-operand of swapped QK^T), prescaled by 1/8 (RNE, once)
    bf16x8 qf0, qf1;
    {
        const float* qbase = qp + ((size_t)bh * SEQ + qrow) * DH + g * 8;
        #pragma unroll
        for (int j = 0; j < 8; ++j) {
            qf0[j] = (short)f2bf(qbase[j]      * 0.125f);
            qf1[j] = (short)f2bf(qbase[32 + j] * 0.125f);
        }
    }

    auto load_raw = [&](int kb, RawT<ISBYTE>& R) {
        #pragma unroll
        for (int mb = 0; mb < 2; ++mb) {
            const float* arow = kbh + (size_t)(kb + 16 * mb + l15) * DH + g * 8;
            R.k[mb][0] = *(const f32x4*)(arow);
            R.k[mb][1] = *(const f32x4*)(arow + 4);
            R.k[mb][2] = *(const f32x4*)(arow + 32);
            R.k[mb][3] = *(const f32x4*)(arow + 36);
            const int kloc = kb + 16 * mb + 4 * g;
            R.bias[mb] = *(const f32x4*)(biasRow + kloc);     // cached: b-pair shares L2
            if constexpr (ISBYTE) R.m8[mb] = *(const unsigned int*)(maskRowB + kloc);
            else                  R.mi[mb] = *(const i32x4*)(maskRowI + kloc);
        }
    };

    float lsum = 0.0f;

    auto body = [&](const RawT<ISBYTE>& R, int kb) {
        #pragma unroll
        for (int mb = 0; mb < 2; ++mb) {
            union { bf16x8 v; unsigned int u[4]; } A0, A1;
            A0.u[0] = pkt(R.k[mb][0][0], R.k[mb][0][1]);
            A0.u[1] = pkt(R.k[mb][0][2], R.k[mb][0][3]);
            A0.u[2] = pkt(R.k[mb][1][0], R.k[mb][1][1]);
            A0.u[3] = pkt(R.k[mb][1][2], R.k[mb][1][3]);
            A1.u[0] = pkt(R.k[mb][2][0], R.k[mb][2][1]);
            A1.u[1] = pkt(R.k[mb][2][2], R.k[mb][2][3]);
            A1.u[2] = pkt(R.k[mb][3][0], R.k[mb][3][1]);
            A1.u[3] = pkt(R.k[mb][3][2], R.k[mb][3][3]);
            f32x4 c = (f32x4){0.f, 0.f, 0.f, 0.f};            // bias OFF the MFMA chain
            __builtin_amdgcn_s_setprio(1);
            c = __builtin_amdgcn_mfma_f32_16x16x32_bf16(A0.v, qf0, c, 0, 0, 0);
            c = __builtin_amdgcn_mfma_f32_16x16x32_bf16(A1.v, qf1, c, 0, 0, 0);
            __builtin_amdgcn_s_setprio(0);
            f32x4 pa;
            if constexpr (ISBYTE) {
                const unsigned int m = R.m8[mb];
                #pragma unroll
                for (int j = 0; j < 4; ++j)
                    pa[j] = ((m >> (8 * j)) & 0xFFu) ? 0.0f : __expf(c[j] + R.bias[mb][j]);
            } else {
                #pragma unroll
                for (int j = 0; j < 4; ++j)
                    pa[j] = R.mi[mb][j] ? 0.0f : __expf(c[j] + R.bias[mb][j]);
            }
            lsum += pa[0] + pa[1] + pa[2] + pa[3];
            *(f32x4*)(attnRow + kb + 16 * mb + 4 * g) = pa;   // UNNORMALIZED
        }
    };

    {
        RawT<ISBYTE> RA, RB;
        load_raw(0, RA);
        load_raw(KT, RB);
        for (int kt = 0; kt < NKT; kt += 2) {
            const int kb2 = ((kt + 2) & (NKT - 1)) * KT;
            const int kb3 = ((kt + 3) & (NKT - 1)) * KT;
            body(RA, kt * KT);
            load_raw(kb2, RA);      // distance-2 reissue
            body(RB, kt * KT + KT);
            load_raw(kb3, RB);
        }
    }

    lsum += __shfl_xor(lsum, 16, 64);   // combine the 4 lane-groups of each q-row
    lsum += __shfl_xor(lsum, 32, 64);
    if (g == 0) rinvp[(size_t)bh * SEQ + qrow] = 1.0f / lsum;
}

// ====== kernel 2: normalize attn in place + out = P_norm . V  (fused rescale+PV) ======
// 2 independent waves/block, each: 16 q-rows x full k. P via small LDS; V direct B-frags.
__global__ __launch_bounds__(128)
void sdpa_pv(const float* __restrict__ vp,
             float* __restrict__ attnp,
             const float* __restrict__ rinvp,
             float* __restrict__ outp)
{
    __shared__ __align__(16) unsigned short P_lds[2][16 * 40];  // [q][k-chunk], stride 40

    const int tid  = threadIdx.x;
    const int wid  = tid >> 6;
    const int lane = tid & 63;
    const int l15  = lane & 15;
    const int g    = lane >> 4;
    const int r    = lane >> 2;         // q-row for attn streaming (0..15)
    const int c0   = (lane & 3) * 8;    // col base within 32-k chunk

    const int bid  = blockIdx.x;
    const int orig = (bid & 7) * 256 + (bid >> 3);   // bijective, 2048 blocks
    const int bh   = orig >> 6;                      // 4 bh per XCD -> V fits L2
    const int qt   = (orig & 63) * 2 + wid;

    float* attnBase = attnp + ((size_t)bh * SEQ + qt * 16) * SEQ;
    float* rowPtr   = attnBase + (size_t)r * SEQ;
    const float rv  = rinvp[(size_t)bh * SEQ + qt * 16 + r];
    const float* vbh = vp + (size_t)bh * SEQ * DH;
    unsigned short* plw = &P_lds[wid][0];

    f32x4 accO[4];   // accO[nb][rr] = O[q=16qt+4g+rr][d=16nb+l15] (normalized)
    #pragma unroll
    for (int i = 0; i < 4; ++i) accO[i] = (f32x4){0.f, 0.f, 0.f, 0.f};

    struct Slot { f32x4 a0, a1; float v[4][8]; };

    auto load_slot = [&](int kc, Slot& S) {
        const float* ap = rowPtr + kc * KT + c0;
        S.a0 = *(const f32x4*)ap;
        S.a1 = *(const f32x4*)(ap + 4);
        const float* vb2 = vbh + (size_t)kc * KT * DH + 512 * g + l15;
        #pragma unroll
        for (int nb = 0; nb < 4; ++nb)
            #pragma unroll
            for (int j = 0; j < 8; ++j)
                S.v[nb][j] = vb2[j * 64 + 16 * nb];
    };

    auto body = [&](const Slot& S, int kc) {
        // normalize + write back attn
        f32x4 s0, s1;
        #pragma unroll
        for (int j = 0; j < 4; ++j) { s0[j] = S.a0[j] * rv; s1[j] = S.a1[j] * rv; }
        float* ap = rowPtr + kc * KT + c0;
        *(f32x4*)ap       = s0;
        *(f32x4*)(ap + 4) = s1;
        // P -> LDS (bf16), row r, cols c0..c0+7 of this 32-k chunk
        u32x4 w;
        w[0] = pkt(s0[0], s0[1]);  w[1] = pkt(s0[2], s0[3]);
        w[2] = pkt(s1[0], s1[1]);  w[3] = pkt(s1[2], s1[3]);
        *(u32x4*)(plw + r * 40 + c0) = w;
        // V -> bf16 B-frags
        union { bf16x8 v; unsigned int u[4]; } vf[4];
        #pragma unroll
        for (int nb = 0; nb < 4; ++nb)
            #pragma unroll
            for (int i = 0; i < 4; ++i)
                vf[nb].u[i] = pkt(S.v[nb][2 * i], S.v[nb][2 * i + 1]);
        // A-frag: P[q=l15][k=8g+j]
        bf16x8 pf = *(const bf16x8*)(plw + l15 * 40 + g * 8);
        __builtin_amdgcn_s_setprio(1);
        #pragma unroll
        for (int nb = 0; nb < 4; ++nb)
            accO[nb] = __builtin_amdgcn_mfma_f32_16x16x32_bf16(pf, vf[nb].v, accO[nb], 0, 0, 0);
        __builtin_amdgcn_s_setprio(0);
    };

    {
        Slot SA, SB;
        load_slot(0, SA);
        load_slot(1, SB);
        for (int kc = 0; kc < NKT; kc += 2) {
            const int k2 = (kc + 2) & (NKT - 1);
            const int k3 = (kc + 3) & (NKT - 1);
            body(SA, kc);
            load_slot(k2, SA);      // distance-2 reissue
            body(SB, kc + 1);
            load_slot(k3, SB);
        }
    }

    // out (already normalized): lane holds O[q=4g+rr][d=16nb+l15]
    float* outBase = outp + ((size_t)bh * SEQ + qt * 16) * DH;
    #pragma unroll
    for (int rr = 0; rr < 4; ++rr)
        #pragma unroll
        for (int nb = 0; nb < 4; ++nb)
            outBase[(4 * g + rr) * DH + 16 * nb + l15] = accO[nb][rr];
}

extern "C" void kernel_launch(void* const* d_in, const int* in_sizes, int n_in,
                              void* d_out, int out_size, void* d_ws, size_t ws_size,
                              hipStream_t stream) {
    const float* qp = (const float*)d_in[0];
    const float* kp = (const float*)d_in[1];
    const float* vp = (const float*)d_in[2];
    const void*  mp = d_in[3];
    const float* bp = (const float*)d_in[4];

    float* outp  = (float*)d_out;
    float* attnp = outp + (size_t)BATCH * NH * SEQ * DH;   // out first, then attn (f32)
    float* rinvp = (float*)d_ws;                            // 256 KB scratch

    dim3 grid(2048), block(128);
    // mask layout resolved on-device; mismatched instantiation exits immediately
    sdpa_score<true ><<<grid, block, 0, stream>>>(qp, kp, mp, bp, attnp, rinvp);
    sdpa_score<false><<<grid, block, 0, stream>>>(qp, kp, mp, bp, attnp, rinvp);

    sdpa_pv<<<grid, block, 0, stream>>>(vp, attnp, rinvp, outp);
}

// Round 12
// 815.743 us; speedup vs baseline: 1.0613x; 1.0613x over previous
//
#include <hip/hip_runtime.h>

#define BATCH 2
#define NH    16
#define SEQ   2048
#define DH    64
#define KT    32
#define KHALF (SEQ / 2)
#define NKT2  (KHALF / KT)   // 32 tiles per k-half wave

typedef __attribute__((ext_vector_type(8))) short          bf16x8;
typedef __attribute__((ext_vector_type(4))) float          f32x4;
typedef __attribute__((ext_vector_type(4))) unsigned int   u32x4;
typedef __attribute__((ext_vector_type(4))) int            i32x4;

__device__ __forceinline__ unsigned short f2bf(float f) {   // RNE
    union { float f; unsigned int i; } c;
    c.f = f;
    unsigned int x = c.i;
    x += 0x7fffu + ((x >> 16) & 1u);
    return (unsigned short)(x >> 16);
}
// truncation pack: two f32 -> one u32 of 2 bf16 (round-toward-zero; cheap)
__device__ __forceinline__ unsigned int pkt(float lo, float hi) {
    union { float f; unsigned int u; } a, b;
    a.f = lo; b.f = hi;
    return (b.u & 0xFFFF0000u) | (a.u >> 16);
}

template<bool ISBYTE> struct RawT {
    f32x4 k[2][4];          // [mb][a0lo,a0hi,a1lo,a1hi]
    f32x4 bias[2];
    unsigned int m8[2];     // ISBYTE
    i32x4 mi[2];            // !ISBYTE
};

// ========== kernel 1: scores (k-split x2). attn <- UNNORMALIZED exp(s); lsum atomics ==========
// Each wave: 16 q-rows x ONE k-half (32 tiles). 8192 waves -> 8 waves/SIMD occupancy cap.
template<bool ISBYTE>
__global__ __launch_bounds__(128)
void sdpa_score(const float* __restrict__ qp,
                const float* __restrict__ kp,
                const void*  __restrict__ mp,
                const float* __restrict__ bp,
                float* __restrict__ attnp,
                float* __restrict__ lsump)
{
    const int tid  = threadIdx.x;
    const int wid  = tid >> 6;          // k-half
    const int lane = tid & 63;
    const int l15  = lane & 15;         // q-column (S^T layout of QK^T)
    const int g    = lane >> 4;

    const unsigned int* mw = (const unsigned int*)mp;
    if ((__any((int)(mw[lane & 31] > 1u)) != 0) != ISBYTE) return;

    // XCD swizzle (2 heads/XCD) + b interleaved so bias rows pair-share in L2
    const int bid  = blockIdx.x;
    const int orig = (bid & 7) * 512 + (bid >> 3);   // bijective, 4096 blocks
    const int h    = orig >> 8;                      // 0..15
    const int rem  = orig & 255;
    const int qt   = rem >> 1;                       // 0..127
    const int b    = rem & 1;
    const int bh   = b * NH + h;
    const int qrow = qt * 16 + l15;
    const int k0   = wid * KHALF;

    const float* kbh = kp + (size_t)bh * SEQ * DH;
    const float* biasRow = bp + ((size_t)h * SEQ + qrow) * SEQ;                  // [1,H,S,S]
    const unsigned char* maskRowB = (const unsigned char*)mp + ((size_t)b * SEQ + qrow) * SEQ;
    const int*           maskRowI = (const int*)mp + ((size_t)b * SEQ + qrow) * SEQ;
    float* attnRow = attnp + ((size_t)bh * SEQ + qrow) * SEQ;

    // Q fragments (B-operand of swapped QK^T), prescaled by 1/8 (RNE, once)
    bf16x8 qf0, qf1;
    {
        const float* qbase = qp + ((size_t)bh * SEQ + qrow) * DH + g * 8;
        #pragma unroll
        for (int j = 0; j < 8; ++j) {
            qf0[j] = (short)f2bf(qbase[j]      * 0.125f);
            qf1[j] = (short)f2bf(qbase[32 + j] * 0.125f);
        }
    }

    auto load_raw = [&](int kb, RawT<ISBYTE>& R) {   // kb absolute
        #pragma unroll
        for (int mb = 0; mb < 2; ++mb) {
            const float* arow = kbh + (size_t)(kb + 16 * mb + l15) * DH + g * 8;
            R.k[mb][0] = *(const f32x4*)(arow);
            R.k[mb][1] = *(const f32x4*)(arow + 4);
            R.k[mb][2] = *(const f32x4*)(arow + 32);
            R.k[mb][3] = *(const f32x4*)(arow + 36);
            const int kloc = kb + 16 * mb + 4 * g;
            R.bias[mb] = *(const f32x4*)(biasRow + kloc);     // cached: b-pair shares L2
            if constexpr (ISBYTE) R.m8[mb] = *(const unsigned int*)(maskRowB + kloc);
            else                  R.mi[mb] = *(const i32x4*)(maskRowI + kloc);
        }
    };

    float lsum = 0.0f;

    auto body = [&](const RawT<ISBYTE>& R, int kb) {
        #pragma unroll
        for (int mb = 0; mb < 2; ++mb) {
            union { bf16x8 v; unsigned int u[4]; } A0, A1;
            A0.u[0] = pkt(R.k[mb][0][0], R.k[mb][0][1]);
            A0.u[1] = pkt(R.k[mb][0][2], R.k[mb][0][3]);
            A0.u[2] = pkt(R.k[mb][1][0], R.k[mb][1][1]);
            A0.u[3] = pkt(R.k[mb][1][2], R.k[mb][1][3]);
            A1.u[0] = pkt(R.k[mb][2][0], R.k[mb][2][1]);
            A1.u[1] = pkt(R.k[mb][2][2], R.k[mb][2][3]);
            A1.u[2] = pkt(R.k[mb][3][0], R.k[mb][3][1]);
            A1.u[3] = pkt(R.k[mb][3][2], R.k[mb][3][3]);
            f32x4 c = (f32x4){0.f, 0.f, 0.f, 0.f};            // bias OFF the MFMA chain
            __builtin_amdgcn_s_setprio(1);
            c = __builtin_amdgcn_mfma_f32_16x16x32_bf16(A0.v, qf0, c, 0, 0, 0);
            c = __builtin_amdgcn_mfma_f32_16x16x32_bf16(A1.v, qf1, c, 0, 0, 0);
            __builtin_amdgcn_s_setprio(0);
            f32x4 pa;
            if constexpr (ISBYTE) {
                const unsigned int m = R.m8[mb];
                #pragma unroll
                for (int j = 0; j < 4; ++j)
                    pa[j] = ((m >> (8 * j)) & 0xFFu) ? 0.0f : __expf(c[j] + R.bias[mb][j]);
            } else {
                #pragma unroll
                for (int j = 0; j < 4; ++j)
                    pa[j] = R.mi[mb][j] ? 0.0f : __expf(c[j] + R.bias[mb][j]);
            }
            lsum += pa[0] + pa[1] + pa[2] + pa[3];
            *(f32x4*)(attnRow + kb + 16 * mb + 4 * g) = pa;   // UNNORMALIZED
        }
    };

    {
        RawT<ISBYTE> RA, RB;
        load_raw(k0, RA);
        load_raw(k0 + KT, RB);
        for (int kt = 0; kt < NKT2; kt += 2) {
            const int kb2 = k0 + (((kt + 2) & (NKT2 - 1)) * KT);
            const int kb3 = k0 + (((kt + 3) & (NKT2 - 1)) * KT);
            body(RA, k0 + kt * KT);
            load_raw(kb2, RA);      // distance-2 reissue
            body(RB, k0 + kt * KT + KT);
            load_raw(kb3, RB);
        }
    }

    lsum += __shfl_xor(lsum, 16, 64);   // combine the 4 lane-groups of each q-row
    lsum += __shfl_xor(lsum, 32, 64);
    // exactly 2 atomic adds per row (one per k-half): commutative -> bitwise deterministic
    if (g == 0) atomicAdd(&lsump[(size_t)bh * SEQ + qrow], lsum);
}

// ========== kernel 2: normalize attn in place + out = P_norm . V (k-split x2) ==========
// 2 waves/block = the two k-halves of one q-tile; accO combined via LDS at the end.
__global__ __launch_bounds__(128)
void sdpa_pv(const float* __restrict__ vp,
             float* __restrict__ attnp,
             const float* __restrict__ lsump,
             float* __restrict__ outp)
{
    __shared__ __align__(16) unsigned short P_lds[2][16 * 40];  // per-wave [q][k-chunk]
    __shared__ float OA[16][65];                                // accO exchange (padded)

    const int tid  = threadIdx.x;
    const int wid  = tid >> 6;          // k-half
    const int lane = tid & 63;
    const int l15  = lane & 15;
    const int g    = lane >> 4;
    const int r    = lane >> 2;         // q-row for attn streaming (0..15)
    const int c0   = (lane & 3) * 8;    // col base within 32-k chunk

    const int bid  = blockIdx.x;
    const int orig = (bid & 7) * 512 + (bid >> 3);   // bijective, 4096 blocks
    const int bh   = orig >> 7;                      // 4 bh per XCD -> V fits L2
    const int qt   = orig & 127;
    const int k0   = wid * KHALF;

    float* rowPtr   = attnp + ((size_t)bh * SEQ + qt * 16 + r) * SEQ + k0;
    const float rv  = 1.0f / lsump[(size_t)bh * SEQ + qt * 16 + r];
    const float* vbh = vp + (size_t)bh * SEQ * DH + (size_t)k0 * DH;
    unsigned short* plw = &P_lds[wid][0];

    f32x4 accO[4];   // accO[nb][rr] = O[q=16qt+4g+rr][d=16nb+l15] (normalized, this k-half)
    #pragma unroll
    for (int i = 0; i < 4; ++i) accO[i] = (f32x4){0.f, 0.f, 0.f, 0.f};

    struct Slot { f32x4 a0, a1; float v[4][8]; };

    auto load_slot = [&](int kc, Slot& S) {          // kc in [0,32) within this half
        const float* ap = rowPtr + kc * KT + c0;
        S.a0 = *(const f32x4*)ap;
        S.a1 = *(const f32x4*)(ap + 4);
        const float* vb2 = vbh + (size_t)kc * KT * DH + 512 * g + l15;
        #pragma unroll
        for (int nb = 0; nb < 4; ++nb)
            #pragma unroll
            for (int j = 0; j < 8; ++j)
                S.v[nb][j] = vb2[j * 64 + 16 * nb];
    };

    auto body = [&](const Slot& S, int kc) {
        f32x4 s0, s1;
        #pragma unroll
        for (int j = 0; j < 4; ++j) { s0[j] = S.a0[j] * rv; s1[j] = S.a1[j] * rv; }
        float* ap = rowPtr + kc * KT + c0;
        *(f32x4*)ap       = s0;                      // normalized attn write-back
        *(f32x4*)(ap + 4) = s1;
        u32x4 w;
        w[0] = pkt(s0[0], s0[1]);  w[1] = pkt(s0[2], s0[3]);
        w[2] = pkt(s1[0], s1[1]);  w[3] = pkt(s1[2], s1[3]);
        *(u32x4*)(plw + r * 40 + c0) = w;            // P (bf16) -> LDS [q][k]
        union { bf16x8 v; unsigned int u[4]; } vf[4];
        #pragma unroll
        for (int nb = 0; nb < 4; ++nb)
            #pragma unroll
            for (int i = 0; i < 4; ++i)
                vf[nb].u[i] = pkt(S.v[nb][2 * i], S.v[nb][2 * i + 1]);
        bf16x8 pf = *(const bf16x8*)(plw + l15 * 40 + g * 8);   // A-frag P[q=l15][k=8g+j]
        __builtin_amdgcn_s_setprio(1);
        #pragma unroll
        for (int nb = 0; nb < 4; ++nb)
            accO[nb] = __builtin_amdgcn_mfma_f32_16x16x32_bf16(pf, vf[nb].v, accO[nb], 0, 0, 0);
        __builtin_amdgcn_s_setprio(0);
    };

    {
        Slot SA, SB;
        load_slot(0, SA);
        load_slot(1, SB);
        for (int kc = 0; kc < NKT2; kc += 2) {
            const int k2 = (kc + 2) & (NKT2 - 1);
            const int k3 = (kc + 3) & (NKT2 - 1);
            body(SA, kc);
            load_slot(k2, SA);      // distance-2 reissue
            body(SB, kc + 1);
            load_slot(k3, SB);
        }
    }

    // cross-wave combine: wave1 deposits its half, wave0 adds and writes out
    if (wid == 1) {
        #pragma unroll
        for (int rr = 0; rr < 4; ++rr)
            #pragma unroll
            for (int nb = 0; nb < 4; ++nb)
                OA[4 * g + rr][16 * nb + l15] = accO[nb][rr];
    }
    __syncthreads();

    if (wid == 0) {
        float* outBase = outp + ((size_t)bh * SEQ + qt * 16) * DH;
        #pragma unroll
        for (int rr = 0; rr < 4; ++rr)
            #pragma unroll
            for (int nb = 0; nb < 4; ++nb)
                outBase[(4 * g + rr) * DH + 16 * nb + l15] =
                    accO[nb][rr] + OA[4 * g + rr][16 * nb + l15];
    }
}

extern "C" void kernel_launch(void* const* d_in, const int* in_sizes, int n_in,
                              void* d_out, int out_size, void* d_ws, size_t ws_size,
                              hipStream_t stream) {
    const float* qp = (const float*)d_in[0];
    const float* kp = (const float*)d_in[1];
    const float* vp = (const float*)d_in[2];
    const void*  mp = d_in[3];
    const float* bp = (const float*)d_in[4];

    float* outp  = (float*)d_out;
    float* attnp = outp + (size_t)BATCH * NH * SEQ * DH;   // out first, then attn (f32)
    float* lsump = (float*)d_ws;                            // 256 KB scratch (row sums)

    // zero lsum accumulators (graph-capture-safe async memset on stream)
    hipMemsetAsync(lsump, 0, (size_t)BATCH * NH * SEQ * sizeof(float), stream);

    dim3 grid(4096), block(128);
    // mask layout resolved on-device; mismatched instantiation exits immediately
    sdpa_score<true ><<<grid, block, 0, stream>>>(qp, kp, mp, bp, attnp, lsump);
    sdpa_score<false><<<grid, block, 0, stream>>>(qp, kp, mp, bp, attnp, lsump);

    sdpa_pv<<<grid, block, 0, stream>>>(vp, attnp, lsump, outp);
}